// Round 4
// baseline (939.662 us; speedup 1.0000x reference)
//
#include <hip/hip_runtime.h>

#define DEVI __device__ __forceinline__

typedef short v8s __attribute__((ext_vector_type(8)));
typedef float v4f __attribute__((ext_vector_type(4)));
typedef unsigned short u16;

DEVI float bf2f(short s) {
  union { unsigned u; float f; } cv;
  cv.u = ((unsigned)(u16)s) << 16;
  return cv.f;
}
DEVI short f2bf(float f) {
  union { float f; unsigned u; } cv; cv.f = f;
  unsigned u = cv.u;
  return (short)((u + 0x7FFFu + ((u >> 16) & 1u)) >> 16);
}

// ---------------- prep: transpose + cast weights to bf16 ----------------
__global__ void prep_weights(const float* __restrict__ Wq, const float* __restrict__ Wk,
                             const float* __restrict__ Wv, const float* __restrict__ Wout,
                             short* __restrict__ WcT, short* __restrict__ WoT) {
  int n = blockIdx.x;
  int k = threadIdx.x;
  float v;
  if (n < 256)      v = Wq[k * 256 + n];
  else if (n < 512) v = Wk[k * 256 + (n - 256)];
  else              v = Wv[k * 256 + (n - 512)];
  WcT[n * 256 + k] = f2bf(v);
  if (n < 256) WoT[n * 256 + k] = f2bf(Wout[k * 256 + n]);
}

// ---------------- QKV projection GEMM: A-resident full-K, n-loop inside ----------------
// block: 128 rows, K=256 resident; loops 6 n-tiles of 128. LDS = 64+64 KB.
__launch_bounds__(256, 1)
__global__ void proj_gemm(const float* __restrict__ x, const short* __restrict__ WcT,
                          const float* __restrict__ pos_emb,
                          short* __restrict__ Qb, short* __restrict__ Kb,
                          short* __restrict__ Vb) {
  __shared__ short As[128 * 256];
  __shared__ short Bs[128 * 256];
  const int t = threadIdx.x;
  const int m0 = blockIdx.x * 128;
  const int wave = t >> 6, lane = t & 63;
  const int wm = (wave & 1) * 64, wn = (wave >> 1) * 64;
  const int lr = lane & 15, g = lane >> 4;

  for (int i = 0; i < 32; ++i) {
    int idx = t + i * 256;
    int row = idx >> 6, c4 = idx & 63;
    float4 vv = *reinterpret_cast<const float4*>(x + (size_t)(m0 + row) * 256 + c4 * 4);
    short4 pk;
    pk.x = f2bf(vv.x); pk.y = f2bf(vv.y); pk.z = f2bf(vv.z); pk.w = f2bf(vv.w);
    int byte = (row * 512 + c4 * 8) ^ ((row & 7) << 4);
    *reinterpret_cast<short4*>(reinterpret_cast<char*>(As) + byte) = pk;
  }

  for (int nt = 0; nt < 6; ++nt) {
    for (int i = 0; i < 16; ++i) {
      int idx = t + i * 256;
      int rn = idx >> 5, c = idx & 31;
      v8s vv = *reinterpret_cast<const v8s*>(WcT + (size_t)(nt * 128 + rn) * 256 + c * 8);
      int byte = (rn * 512 + c * 16) ^ ((rn & 7) << 4);
      *reinterpret_cast<v8s*>(reinterpret_cast<char*>(Bs) + byte) = vv;
    }
    __syncthreads();

    v4f acc[4][4];
#pragma unroll
    for (int i = 0; i < 4; ++i)
#pragma unroll
      for (int j = 0; j < 4; ++j) acc[i][j] = (v4f){0.f, 0.f, 0.f, 0.f};

    for (int ks = 0; ks < 8; ++ks) {
      v8s af[4], bfr[4];
#pragma unroll
      for (int i = 0; i < 4; ++i) {
        int row = wm + i * 16 + lr;
        int byte = (row * 512 + ks * 64 + g * 16) ^ ((row & 7) << 4);
        af[i] = *reinterpret_cast<const v8s*>(reinterpret_cast<const char*>(As) + byte);
      }
#pragma unroll
      for (int j = 0; j < 4; ++j) {
        int rn = wn + j * 16 + lr;
        int byte = (rn * 512 + ks * 64 + g * 16) ^ ((rn & 7) << 4);
        bfr[j] = *reinterpret_cast<const v8s*>(reinterpret_cast<const char*>(Bs) + byte);
      }
#pragma unroll
      for (int i = 0; i < 4; ++i)
#pragma unroll
        for (int j = 0; j < 4; ++j)
          acc[i][j] = __builtin_amdgcn_mfma_f32_16x16x32_bf16(af[i], bfr[j], acc[i][j], 0, 0, 0);
    }
    __syncthreads();

#pragma unroll
    for (int i = 0; i < 4; ++i) {
#pragma unroll
      for (int j = 0; j < 4; ++j) {
        int colg = nt * 128 + wn + j * 16 + lr;
#pragma unroll
        for (int r = 0; r < 4; ++r) {
          int p = m0 + wm + i * 16 + g * 4 + r;
          float v = acc[i][j][r];
          if (nt < 2) {
            int yy = (p >> 7) & 127, xx = p & 127;
            int qi = (yy - min(max(yy, 2), 125) + 2) * 5 + (xx - min(max(xx, 2), 125) + 2);
            v += pos_emb[qi * 256 + colg];
            Qb[(size_t)p * 256 + colg] = f2bf(v);
          } else if (nt < 4) {
            Kb[(size_t)p * 256 + (colg - 256)] = f2bf(v);
          } else {
            Vb[(size_t)p * 256 + (colg - 512)] = f2bf(v);
          }
        }
      }
    }
  }
}

// ---------------- attention: split-F, qpe staged through LDS, rolled loops ----------------
// thread = (position, head, f-half). block = 4x4 positions * 8 heads * 2 halves = 256 threads.
__launch_bounds__(256, 6)
__global__ void attn_kernel(const short* __restrict__ Qb, const short* __restrict__ Kb,
                            const short* __restrict__ Vb, const float* __restrict__ pos_emb,
                            short* __restrict__ ACC) {
  __shared__ short peb16[25 * 256];   // pos_emb in bf16
  __shared__ float qsm[128 * 25];     // per-(pos,head) pe-dot, SCALE applied

  // stage pe (f32 global -> bf16 LDS)
  for (int i = threadIdx.x; i < 1600; i += 256) {
    float4 vv = reinterpret_cast<const float4*>(pos_emb)[i];
    short4 pk;
    pk.x = f2bf(vv.x); pk.y = f2bf(vv.y); pk.z = f2bf(vv.z); pk.w = f2bf(vv.w);
    *reinterpret_cast<short4*>(peb16 + i * 4) = pk;
  }

  const int t = threadIdx.x;
  const int half = t & 1, h = (t >> 1) & 7, pl = t >> 4;
  const int pair = t >> 1;
  const int id = blockIdx.x;
  const int b = id & 7;                 // batch -> XCD
  const int local = id >> 3;
  const int bx = local & 31, by = local >> 5;
  const int xx = bx * 4 + (pl & 3);
  const int yy = by * 4 + (pl >> 2);
  const int yc = min(max(yy, 2), 125), xc = min(max(xx, 2), 125);
  const int fo = h * 32 + half * 16;    // this thread's 16-f slice
  const size_t pbase = ((size_t)((b * 128 + yy) * 128 + xx)) * 256 + fo;
  const size_t cbase = ((size_t)((b * 128 + yc) * 128 + xc)) * 256 + fo;
  const float SCALE = 0.17677669529663689f;  // 1/sqrt(32)

  // load Q slice (global; no LDS dep)
  float q[16];
  {
    v8s q0 = *reinterpret_cast<const v8s*>(Qb + pbase);
    v8s q1 = *reinterpret_cast<const v8s*>(Qb + pbase + 8);
#pragma unroll
    for (int e = 0; e < 8; ++e) { q[e] = bf2f(q0[e]); q[8 + e] = bf2f(q1[e]); }
  }
  __syncthreads();

  // phase 2: qpe -> qsm (rolled; write each value immediately, no live array)
#pragma unroll 1
  for (int s = 0; s < 25; ++s) {
    const short* pp = peb16 + s * 256 + fo;
    v8s p0 = *reinterpret_cast<const v8s*>(pp);
    v8s p1 = *reinterpret_cast<const v8s*>(pp + 8);
    float d0 = 0.f, d1 = 0.f, d2 = 0.f, d3 = 0.f;
#pragma unroll
    for (int e = 0; e < 4; ++e) {
      d0 = fmaf(q[e], bf2f(p0[e]), d0);
      d1 = fmaf(q[4 + e], bf2f(p0[4 + e]), d1);
      d2 = fmaf(q[8 + e], bf2f(p1[e]), d2);
      d3 = fmaf(q[12 + e], bf2f(p1[4 + e]), d3);
    }
    float d = (d0 + d1) + (d2 + d3);
    float full = d + __shfl_xor(d, 1);
    if (!half) qsm[pair * 25 + s] = full * SCALE;
  }
  __syncthreads();

  float l = 0.f;
  float oa[16];
#pragma unroll
  for (int f = 0; f < 16; ++f) oa[f] = 0.f;

  const short* kb = Kb + cbase;
  const short* vb = Vb + cbase;

#pragma unroll 1
  for (int dy = -2; dy <= 2; ++dy) {
    const short* krow = kb + dy * (128 * 256);
    const short* vrow = vb + dy * (128 * 256);
    const int sbase = (dy + 2) * 5 + 2;
#pragma unroll
    for (int dx = -2; dx <= 2; ++dx) {
      const short* kp = krow + dx * 256;
      const short* vp = vrow + dx * 256;
      v8s k0 = *reinterpret_cast<const v8s*>(kp);
      v8s k1 = *reinterpret_cast<const v8s*>(kp + 8);
      v8s v0 = *reinterpret_cast<const v8s*>(vp);
      v8s v1 = *reinterpret_cast<const v8s*>(vp + 8);
      float d0 = 0.f, d1 = 0.f, d2 = 0.f, d3 = 0.f;
#pragma unroll
      for (int e = 0; e < 4; ++e) {
        d0 = fmaf(q[e], bf2f(k0[e]), d0);
        d1 = fmaf(q[4 + e], bf2f(k0[4 + e]), d1);
        d2 = fmaf(q[8 + e], bf2f(k1[e]), d2);
        d3 = fmaf(q[12 + e], bf2f(k1[4 + e]), d3);
      }
      float part = ((d0 + d1) + (d2 + d3)) * SCALE;
      float sc_ = part + __shfl_xor(part, 1) + qsm[pair * 25 + sbase + dx];
      float w = __expf(sc_);
      l += w;
#pragma unroll
      for (int e = 0; e < 8; ++e) oa[e] = fmaf(w, bf2f(v0[e]), oa[e]);
#pragma unroll
      for (int e = 0; e < 8; ++e) oa[8 + e] = fmaf(w, bf2f(v1[e]), oa[8 + e]);
    }
  }

  float inv = 1.f / l;
  v8s o0, o1;
#pragma unroll
  for (int e = 0; e < 8; ++e) { o0[e] = f2bf(oa[e] * inv); o1[e] = f2bf(oa[8 + e] * inv); }
  *reinterpret_cast<v8s*>(ACC + pbase) = o0;
  *reinterpret_cast<v8s*>(ACC + pbase + 8) = o1;
}

// ---------------- output projection GEMM: A-resident full-K, 2 n-tiles ----------------
__launch_bounds__(256, 1)
__global__ void out_gemm(const short* __restrict__ A, const short* __restrict__ WoT,
                         float* __restrict__ out) {
  __shared__ short As[128 * 256];
  __shared__ short Bs[128 * 256];
  const int t = threadIdx.x;
  const int m0 = blockIdx.x * 128;
  const int wave = t >> 6, lane = t & 63;
  const int wm = (wave & 1) * 64, wn = (wave >> 1) * 64;
  const int lr = lane & 15, g = lane >> 4;

  for (int i = 0; i < 16; ++i) {
    int idx = t + i * 256;
    int rn = idx >> 5, c = idx & 31;
    v8s vv = *reinterpret_cast<const v8s*>(A + (size_t)(m0 + rn) * 256 + c * 8);
    int byte = (rn * 512 + c * 16) ^ ((rn & 7) << 4);
    *reinterpret_cast<v8s*>(reinterpret_cast<char*>(As) + byte) = vv;
  }

  for (int nt = 0; nt < 2; ++nt) {
    for (int i = 0; i < 16; ++i) {
      int idx = t + i * 256;
      int rn = idx >> 5, c = idx & 31;
      v8s vv = *reinterpret_cast<const v8s*>(WoT + (size_t)(nt * 128 + rn) * 256 + c * 8);
      int byte = (rn * 512 + c * 16) ^ ((rn & 7) << 4);
      *reinterpret_cast<v8s*>(reinterpret_cast<char*>(Bs) + byte) = vv;
    }
    __syncthreads();

    v4f acc[4][4];
#pragma unroll
    for (int i = 0; i < 4; ++i)
#pragma unroll
      for (int j = 0; j < 4; ++j) acc[i][j] = (v4f){0.f, 0.f, 0.f, 0.f};

    for (int ks = 0; ks < 8; ++ks) {
      v8s af[4], bfr[4];
#pragma unroll
      for (int i = 0; i < 4; ++i) {
        int row = wm + i * 16 + lr;
        int byte = (row * 512 + ks * 64 + g * 16) ^ ((row & 7) << 4);
        af[i] = *reinterpret_cast<const v8s*>(reinterpret_cast<const char*>(As) + byte);
      }
#pragma unroll
      for (int j = 0; j < 4; ++j) {
        int rn = wn + j * 16 + lr;
        int byte = (rn * 512 + ks * 64 + g * 16) ^ ((rn & 7) << 4);
        bfr[j] = *reinterpret_cast<const v8s*>(reinterpret_cast<const char*>(Bs) + byte);
      }
#pragma unroll
      for (int i = 0; i < 4; ++i)
#pragma unroll
        for (int j = 0; j < 4; ++j)
          acc[i][j] = __builtin_amdgcn_mfma_f32_16x16x32_bf16(af[i], bfr[j], acc[i][j], 0, 0, 0);
    }
    __syncthreads();

#pragma unroll
    for (int i = 0; i < 4; ++i) {
#pragma unroll
      for (int j = 0; j < 4; ++j) {
        int colg = nt * 128 + wn + j * 16 + lr;
#pragma unroll
        for (int r = 0; r < 4; ++r) {
          int p = m0 + wm + i * 16 + g * 4 + r;
          out[(size_t)p * 256 + colg] = acc[i][j][r];
        }
      }
    }
  }
}

extern "C" void kernel_launch(void* const* d_in, const int* in_sizes, int n_in,
                              void* d_out, int out_size, void* d_ws, size_t ws_size,
                              hipStream_t stream) {
  const float* x       = (const float*)d_in[0];
  const float* Wq      = (const float*)d_in[1];
  const float* Wk      = (const float*)d_in[2];
  const float* Wv      = (const float*)d_in[3];
  const float* Wout    = (const float*)d_in[4];
  const float* pos_emb = (const float*)d_in[5];
  float* out = (float*)d_out;

  char* ws = (char*)d_ws;
  short* WcT  = (short*)ws;                       // 768*256*2   = 393216 B
  short* WoT  = (short*)(ws + 393216);            // 256*256*2   = 131072 B
  short* Qb   = (short*)(ws + 524288);            // 131072*256*2 each
  short* Kb   = Qb + (size_t)131072 * 256;
  short* Vb   = Kb + (size_t)131072 * 256;
  short* ACCb = Vb + (size_t)131072 * 256;

  prep_weights<<<768, 256, 0, stream>>>(Wq, Wk, Wv, Wout, WcT, WoT);
  proj_gemm<<<1024, 256, 0, stream>>>(x, WcT, pos_emb, Qb, Kb, Vb);
  attn_kernel<<<8192, 256, 0, stream>>>(Qb, Kb, Vb, pos_emb, ACCb);
  out_gemm<<<1024, 256, 0, stream>>>(ACCb, WoT, out);
}

// Round 5
// 454.127 us; speedup vs baseline: 2.0692x; 2.0692x over previous
//
#include <hip/hip_runtime.h>

#define DEVI __device__ __forceinline__

typedef short v8s __attribute__((ext_vector_type(8)));
typedef float v4f __attribute__((ext_vector_type(4)));
typedef unsigned short u16;

DEVI float bf2f(short s) {
  union { unsigned u; float f; } cv;
  cv.u = ((unsigned)(u16)s) << 16;
  return cv.f;
}
DEVI short f2bf(float f) {
  union { float f; unsigned u; } cv; cv.f = f;
  unsigned u = cv.u;
  return (short)((u + 0x7FFFu + ((u >> 16) & 1u)) >> 16);
}

// ---------------- prep: transpose + cast weights to bf16 ----------------
__global__ void prep_weights(const float* __restrict__ Wq, const float* __restrict__ Wk,
                             const float* __restrict__ Wv, const float* __restrict__ Wout,
                             short* __restrict__ WcT, short* __restrict__ WoT) {
  int n = blockIdx.x;
  int k = threadIdx.x;
  float v;
  if (n < 256)      v = Wq[k * 256 + n];
  else if (n < 512) v = Wk[k * 256 + (n - 256)];
  else              v = Wv[k * 256 + (n - 512)];
  WcT[n * 256 + k] = f2bf(v);
  if (n < 256) WoT[n * 256 + k] = f2bf(Wout[k * 256 + n]);
}

// ---------------- QKV projection GEMM: A-resident full-K, n-loop inside ----------------
__launch_bounds__(256, 1)
__global__ void proj_gemm(const float* __restrict__ x, const short* __restrict__ WcT,
                          const float* __restrict__ pos_emb,
                          short* __restrict__ Qb, short* __restrict__ Kb,
                          short* __restrict__ Vb) {
  __shared__ short As[128 * 256];
  __shared__ short Bs[128 * 256];
  const int t = threadIdx.x;
  const int m0 = blockIdx.x * 128;
  const int wave = t >> 6, lane = t & 63;
  const int wm = (wave & 1) * 64, wn = (wave >> 1) * 64;
  const int lr = lane & 15, g = lane >> 4;

  for (int i = 0; i < 32; ++i) {
    int idx = t + i * 256;
    int row = idx >> 6, c4 = idx & 63;
    float4 vv = *reinterpret_cast<const float4*>(x + (size_t)(m0 + row) * 256 + c4 * 4);
    short4 pk;
    pk.x = f2bf(vv.x); pk.y = f2bf(vv.y); pk.z = f2bf(vv.z); pk.w = f2bf(vv.w);
    int byte = (row * 512 + c4 * 8) ^ ((row & 7) << 4);
    *reinterpret_cast<short4*>(reinterpret_cast<char*>(As) + byte) = pk;
  }

  for (int nt = 0; nt < 6; ++nt) {
    for (int i = 0; i < 16; ++i) {
      int idx = t + i * 256;
      int rn = idx >> 5, c = idx & 31;
      v8s vv = *reinterpret_cast<const v8s*>(WcT + (size_t)(nt * 128 + rn) * 256 + c * 8);
      int byte = (rn * 512 + c * 16) ^ ((rn & 7) << 4);
      *reinterpret_cast<v8s*>(reinterpret_cast<char*>(Bs) + byte) = vv;
    }
    __syncthreads();

    v4f acc[4][4];
#pragma unroll
    for (int i = 0; i < 4; ++i)
#pragma unroll
      for (int j = 0; j < 4; ++j) acc[i][j] = (v4f){0.f, 0.f, 0.f, 0.f};

    for (int ks = 0; ks < 8; ++ks) {
      v8s af[4], bfr[4];
#pragma unroll
      for (int i = 0; i < 4; ++i) {
        int row = wm + i * 16 + lr;
        int byte = (row * 512 + ks * 64 + g * 16) ^ ((row & 7) << 4);
        af[i] = *reinterpret_cast<const v8s*>(reinterpret_cast<const char*>(As) + byte);
      }
#pragma unroll
      for (int j = 0; j < 4; ++j) {
        int rn = wn + j * 16 + lr;
        int byte = (rn * 512 + ks * 64 + g * 16) ^ ((rn & 7) << 4);
        bfr[j] = *reinterpret_cast<const v8s*>(reinterpret_cast<const char*>(Bs) + byte);
      }
#pragma unroll
      for (int i = 0; i < 4; ++i)
#pragma unroll
        for (int j = 0; j < 4; ++j)
          acc[i][j] = __builtin_amdgcn_mfma_f32_16x16x32_bf16(af[i], bfr[j], acc[i][j], 0, 0, 0);
    }
    __syncthreads();

#pragma unroll
    for (int i = 0; i < 4; ++i) {
#pragma unroll
      for (int j = 0; j < 4; ++j) {
        int colg = nt * 128 + wn + j * 16 + lr;
#pragma unroll
        for (int r = 0; r < 4; ++r) {
          int p = m0 + wm + i * 16 + g * 4 + r;
          float v = acc[i][j][r];
          if (nt < 2) {
            int yy = (p >> 7) & 127, xx = p & 127;
            int qi = (yy - min(max(yy, 2), 125) + 2) * 5 + (xx - min(max(xx, 2), 125) + 2);
            v += pos_emb[qi * 256 + colg];
            Qb[(size_t)p * 256 + colg] = f2bf(v);
          } else if (nt < 4) {
            Kb[(size_t)p * 256 + (colg - 256)] = f2bf(v);
          } else {
            Vb[(size_t)p * 256 + (colg - 512)] = f2bf(v);
          }
        }
      }
    }
  }
}

// ---------------- attention: split-F, fused pe-dot, rolled loops, no spill ----------------
// thread = (position, head, f-half). block = 4x4 positions * 8 heads * 2 halves = 256 threads.
__launch_bounds__(256, 4)
__global__ void attn_kernel(const short* __restrict__ Qb, const short* __restrict__ Kb,
                            const short* __restrict__ Vb, const float* __restrict__ pos_emb,
                            short* __restrict__ ACC) {
  __shared__ float pe[25 * 256];   // f32, head-slice XOR swizzle (R2-proven, conflict-free)
  for (int i = threadIdx.x; i < 1600; i += 256) {
    float4 vv = reinterpret_cast<const float4*>(pos_emb)[i];
    int w = i * 4;                  // word index: s*256 + f, f 4-aligned
    int f = w & 255;
    int dst = (w & ~255) + (f ^ ((f >> 5) << 2));   // h = f>>5; XOR 4h within head slice
    *reinterpret_cast<float4*>(pe + dst) = vv;
  }

  const int t = threadIdx.x;
  const int half = t & 1, h = (t >> 1) & 7, pl = t >> 4;
  const int id = blockIdx.x;
  const int b = id & 7;                 // batch -> XCD
  const int local = id >> 3;
  const int bx = local & 31, by = local >> 5;
  const int xx = bx * 4 + (pl & 3);
  const int yy = by * 4 + (pl >> 2);
  const int yc = min(max(yy, 2), 125), xc = min(max(xx, 2), 125);
  const int fo = h * 32 + half * 16;    // this thread's 16-f slice
  const int hx4 = h << 2;
  const size_t pbase = ((size_t)((b * 128 + yy) * 128 + xx)) * 256 + fo;
  const size_t cbase = ((size_t)((b * 128 + yc) * 128 + xc)) * 256 + fo;
  const float SCALE = 0.17677669529663689f;  // 1/sqrt(32)

  // load Q slice (global; no LDS dep)
  float q[16];
  {
    v8s q0 = *reinterpret_cast<const v8s*>(Qb + pbase);
    v8s q1 = *reinterpret_cast<const v8s*>(Qb + pbase + 8);
#pragma unroll
    for (int e = 0; e < 8; ++e) { q[e] = bf2f(q0[e]); q[8 + e] = bf2f(q1[e]); }
  }
  __syncthreads();

  float l = 0.f;
  float oa[16];
#pragma unroll
  for (int f = 0; f < 16; ++f) oa[f] = 0.f;

  const short* kb = Kb + cbase;
  const short* vb = Vb + cbase;
  // pe slice base for this (h, half): word = s*256 + h*32 + ((half*16 + c*4) ^ 4h)
  const float* pb = pe + h * 32;
  const int j0 = (half * 16) ^ hx4;
  const int j1 = (half * 16 + 4) ^ hx4;
  const int j2 = (half * 16 + 8) ^ hx4;
  const int j3 = (half * 16 + 12) ^ hx4;

#pragma unroll 1
  for (int dy = -2; dy <= 2; ++dy) {
    const short* krow = kb + dy * (128 * 256);
    const short* vrow = vb + dy * (128 * 256);
    const float* prow = pb + ((dy + 2) * 5) * 256;
#pragma unroll 1
    for (int dx = -2; dx <= 2; ++dx) {
      const short* kp = krow + dx * 256;
      const short* vp = vrow + dx * 256;
      const float* pp = prow + (dx + 2) * 256;
      v8s k0 = *reinterpret_cast<const v8s*>(kp);
      v8s k1 = *reinterpret_cast<const v8s*>(kp + 8);
      v8s v0 = *reinterpret_cast<const v8s*>(vp);
      v8s v1 = *reinterpret_cast<const v8s*>(vp + 8);
      float4 p0 = *reinterpret_cast<const float4*>(pp + j0);
      float4 p1 = *reinterpret_cast<const float4*>(pp + j1);
      float4 p2 = *reinterpret_cast<const float4*>(pp + j2);
      float4 p3 = *reinterpret_cast<const float4*>(pp + j3);
      float d0 = 0.f, d1 = 0.f, d2 = 0.f, d3 = 0.f;
#pragma unroll
      for (int e = 0; e < 4; ++e) {
        d0 = fmaf(q[e], bf2f(k0[e]), d0);
        d1 = fmaf(q[4 + e], bf2f(k0[4 + e]), d1);
        d2 = fmaf(q[8 + e], bf2f(k1[e]), d2);
        d3 = fmaf(q[12 + e], bf2f(k1[4 + e]), d3);
      }
      // pe contribution: Q·pe_s accumulated into same partials
      d0 = fmaf(q[0], p0.x, d0); d0 = fmaf(q[1], p0.y, d0);
      d0 = fmaf(q[2], p0.z, d0); d0 = fmaf(q[3], p0.w, d0);
      d1 = fmaf(q[4], p1.x, d1); d1 = fmaf(q[5], p1.y, d1);
      d1 = fmaf(q[6], p1.z, d1); d1 = fmaf(q[7], p1.w, d1);
      d2 = fmaf(q[8], p2.x, d2); d2 = fmaf(q[9], p2.y, d2);
      d2 = fmaf(q[10], p2.z, d2); d2 = fmaf(q[11], p2.w, d2);
      d3 = fmaf(q[12], p3.x, d3); d3 = fmaf(q[13], p3.y, d3);
      d3 = fmaf(q[14], p3.z, d3); d3 = fmaf(q[15], p3.w, d3);
      float part = ((d0 + d1) + (d2 + d3)) * SCALE;
      float full = part + __shfl_xor(part, 1);
      float w = __expf(full);
      l += w;
#pragma unroll
      for (int e = 0; e < 8; ++e) oa[e] = fmaf(w, bf2f(v0[e]), oa[e]);
#pragma unroll
      for (int e = 0; e < 8; ++e) oa[8 + e] = fmaf(w, bf2f(v1[e]), oa[8 + e]);
    }
  }

  float inv = 1.f / l;
  v8s o0, o1;
#pragma unroll
  for (int e = 0; e < 8; ++e) { o0[e] = f2bf(oa[e] * inv); o1[e] = f2bf(oa[8 + e] * inv); }
  *reinterpret_cast<v8s*>(ACC + pbase) = o0;
  *reinterpret_cast<v8s*>(ACC + pbase + 8) = o1;
}

// ---------------- output projection GEMM: A-resident full-K, 2 n-tiles ----------------
__launch_bounds__(256, 1)
__global__ void out_gemm(const short* __restrict__ A, const short* __restrict__ WoT,
                         float* __restrict__ out) {
  __shared__ short As[128 * 256];
  __shared__ short Bs[128 * 256];
  const int t = threadIdx.x;
  const int m0 = blockIdx.x * 128;
  const int wave = t >> 6, lane = t & 63;
  const int wm = (wave & 1) * 64, wn = (wave >> 1) * 64;
  const int lr = lane & 15, g = lane >> 4;

  for (int i = 0; i < 16; ++i) {
    int idx = t + i * 256;
    int rn = idx >> 5, c = idx & 31;
    v8s vv = *reinterpret_cast<const v8s*>(A + (size_t)(m0 + rn) * 256 + c * 8);
    int byte = (rn * 512 + c * 16) ^ ((rn & 7) << 4);
    *reinterpret_cast<v8s*>(reinterpret_cast<char*>(As) + byte) = vv;
  }

  for (int nt = 0; nt < 2; ++nt) {
    for (int i = 0; i < 16; ++i) {
      int idx = t + i * 256;
      int rn = idx >> 5, c = idx & 31;
      v8s vv = *reinterpret_cast<const v8s*>(WoT + (size_t)(nt * 128 + rn) * 256 + c * 8);
      int byte = (rn * 512 + c * 16) ^ ((rn & 7) << 4);
      *reinterpret_cast<v8s*>(reinterpret_cast<char*>(Bs) + byte) = vv;
    }
    __syncthreads();

    v4f acc[4][4];
#pragma unroll
    for (int i = 0; i < 4; ++i)
#pragma unroll
      for (int j = 0; j < 4; ++j) acc[i][j] = (v4f){0.f, 0.f, 0.f, 0.f};

    for (int ks = 0; ks < 8; ++ks) {
      v8s af[4], bfr[4];
#pragma unroll
      for (int i = 0; i < 4; ++i) {
        int row = wm + i * 16 + lr;
        int byte = (row * 512 + ks * 64 + g * 16) ^ ((row & 7) << 4);
        af[i] = *reinterpret_cast<const v8s*>(reinterpret_cast<const char*>(As) + byte);
      }
#pragma unroll
      for (int j = 0; j < 4; ++j) {
        int rn = wn + j * 16 + lr;
        int byte = (rn * 512 + ks * 64 + g * 16) ^ ((rn & 7) << 4);
        bfr[j] = *reinterpret_cast<const v8s*>(reinterpret_cast<const char*>(Bs) + byte);
      }
#pragma unroll
      for (int i = 0; i < 4; ++i)
#pragma unroll
        for (int j = 0; j < 4; ++j)
          acc[i][j] = __builtin_amdgcn_mfma_f32_16x16x32_bf16(af[i], bfr[j], acc[i][j], 0, 0, 0);
    }
    __syncthreads();

#pragma unroll
    for (int i = 0; i < 4; ++i) {
#pragma unroll
      for (int j = 0; j < 4; ++j) {
        int colg = nt * 128 + wn + j * 16 + lr;
#pragma unroll
        for (int r = 0; r < 4; ++r) {
          int p = m0 + wm + i * 16 + g * 4 + r;
          out[(size_t)p * 256 + colg] = acc[i][j][r];
        }
      }
    }
  }
}

extern "C" void kernel_launch(void* const* d_in, const int* in_sizes, int n_in,
                              void* d_out, int out_size, void* d_ws, size_t ws_size,
                              hipStream_t stream) {
  const float* x       = (const float*)d_in[0];
  const float* Wq      = (const float*)d_in[1];
  const float* Wk      = (const float*)d_in[2];
  const float* Wv      = (const float*)d_in[3];
  const float* Wout    = (const float*)d_in[4];
  const float* pos_emb = (const float*)d_in[5];
  float* out = (float*)d_out;

  char* ws = (char*)d_ws;
  short* WcT  = (short*)ws;                       // 768*256*2   = 393216 B
  short* WoT  = (short*)(ws + 393216);            // 256*256*2   = 131072 B
  short* Qb   = (short*)(ws + 524288);            // 131072*256*2 each
  short* Kb   = Qb + (size_t)131072 * 256;
  short* Vb   = Kb + (size_t)131072 * 256;
  short* ACCb = Vb + (size_t)131072 * 256;

  prep_weights<<<768, 256, 0, stream>>>(Wq, Wk, Wv, Wout, WcT, WoT);
  proj_gemm<<<1024, 256, 0, stream>>>(x, WcT, pos_emb, Qb, Kb, Vb);
  attn_kernel<<<8192, 256, 0, stream>>>(Qb, Kb, Vb, pos_emb, ACCb);
  out_gemm<<<1024, 256, 0, stream>>>(ACCb, WoT, out);
}

// Round 6
// 374.831 us; speedup vs baseline: 2.5069x; 1.2115x over previous
//
#include <hip/hip_runtime.h>

#define DEVI __device__ __forceinline__

typedef short v8s __attribute__((ext_vector_type(8)));
typedef float v4f __attribute__((ext_vector_type(4)));
typedef unsigned short u16;

typedef __attribute__((address_space(3))) unsigned int lds_u32;
typedef const __attribute__((address_space(1))) unsigned int glb_u32;

DEVI float bf2f(short s) {
  union { unsigned u; float f; } cv;
  cv.u = ((unsigned)(u16)s) << 16;
  return cv.f;
}
DEVI short f2bf(float f) {
  union { float f; unsigned u; } cv; cv.f = f;
  unsigned u = cv.u;
  return (short)((u + 0x7FFFu + ((u >> 16) & 1u)) >> 16);
}
DEVI void gld16(const void* g, void* l) {
  __builtin_amdgcn_global_load_lds((glb_u32*)g, (lds_u32*)l, 16, 0, 0);
}

// ---------------- prep: transpose + cast weights to bf16 ----------------
__global__ void prep_weights(const float* __restrict__ Wq, const float* __restrict__ Wk,
                             const float* __restrict__ Wv, const float* __restrict__ Wout,
                             short* __restrict__ WcT, short* __restrict__ WoT) {
  int n = blockIdx.x;
  int k = threadIdx.x;
  float v;
  if (n < 256)      v = Wq[k * 256 + n];
  else if (n < 512) v = Wk[k * 256 + (n - 256)];
  else              v = Wv[k * 256 + (n - 512)];
  WcT[n * 256 + k] = f2bf(v);
  if (n < 256) WoT[n * 256 + k] = f2bf(Wout[k * 256 + n]);
}

// ---------------- x -> bf16 cast (memory-bound copy) ----------------
__global__ void x_cast(const float* __restrict__ x, short* __restrict__ xb) {
  // 33554432 elems = 4194304 groups of 8; 4096 blocks * 256 thr -> 4 groups/thread
  for (size_t gidx = (size_t)blockIdx.x * 256 + threadIdx.x; gidx < 4194304;
       gidx += (size_t)4096 * 256) {
    const float4* src = reinterpret_cast<const float4*>(x + gidx * 8);
    float4 a = src[0], c = src[1];
    v8s pk;
    pk[0] = f2bf(a.x); pk[1] = f2bf(a.y); pk[2] = f2bf(a.z); pk[3] = f2bf(a.w);
    pk[4] = f2bf(c.x); pk[5] = f2bf(c.y); pk[6] = f2bf(c.z); pk[7] = f2bf(c.w);
    *reinterpret_cast<v8s*>(xb + gidx * 8) = pk;
  }
}

// ---------------- QKV projection GEMM: 128x128, BK=64, dbuf + global_load_lds ----------------
// grid 6144 (1024 m-tiles x 6 n-tiles), XCD-chunked: same-m n-tiles consecutive per XCD.
__launch_bounds__(256, 2)
__global__ void proj_gemm(const short* __restrict__ xb, const short* __restrict__ WcT,
                          const float* __restrict__ pos_emb,
                          short* __restrict__ Qb, short* __restrict__ Kb,
                          short* __restrict__ Vb) {
  __shared__ short As[2][128 * 64];
  __shared__ short Bs[2][128 * 64];
  const int t = threadIdx.x;
  const int bi = blockIdx.x;
  const int xcd = bi & 7;
  const int jj = bi >> 3;
  const int mt = (jj / 6) * 8 + xcd;   // bijective: 6144 % 8 == 0
  const int nt = jj % 6;
  const int m0 = mt * 128, n0 = nt * 128;
  const int wave = t >> 6, lane = t & 63;
  const int wm = (wave & 1) * 64, wn = (wave >> 1) * 64;
  const int lr = lane & 15, g = lane >> 4;

  // gload_lds pre-swizzled source: lane covers row (cc*8 + ro), col bytes (lane&7)*16 ^ (ro<<4)
  const int ro = lane >> 3;
  const int colb = ((lane & 7) * 16) ^ (ro << 4);
  const char* aSrc = reinterpret_cast<const char*>(xb + (size_t)(m0 + ro) * 256) + colb;
  const char* bSrc = reinterpret_cast<const char*>(WcT + (size_t)(n0 + ro) * 256) + colb;

  v4f acc[4][4];
#pragma unroll
  for (int i = 0; i < 4; ++i)
#pragma unroll
    for (int j = 0; j < 4; ++j) acc[i][j] = (v4f){0.f, 0.f, 0.f, 0.f};

  auto stage = [&](int buf, int kt) {
#pragma unroll
    for (int c = 0; c < 4; ++c) {
      int cc = wave * 4 + c;                       // chunk 0..15, 8 rows each
      gld16(aSrc + (size_t)cc * 8 * 512 + kt * 2, (char*)As[buf] + cc * 1024);
      gld16(bSrc + (size_t)cc * 8 * 512 + kt * 2, (char*)Bs[buf] + cc * 1024);
    }
  };
  auto compute = [&](int buf) {
#pragma unroll
    for (int kk = 0; kk < 2; ++kk) {
      v8s af[4], bfr[4];
#pragma unroll
      for (int i = 0; i < 4; ++i) {
        int row = wm + i * 16 + lr;
        int byte = (row * 128 + kk * 64 + g * 16) ^ ((row & 7) << 4);
        af[i] = *reinterpret_cast<const v8s*>(reinterpret_cast<const char*>(As[buf]) + byte);
      }
#pragma unroll
      for (int j = 0; j < 4; ++j) {
        int rn = wn + j * 16 + lr;
        int byte = (rn * 128 + kk * 64 + g * 16) ^ ((rn & 7) << 4);
        bfr[j] = *reinterpret_cast<const v8s*>(reinterpret_cast<const char*>(Bs[buf]) + byte);
      }
#pragma unroll
      for (int i = 0; i < 4; ++i)
#pragma unroll
        for (int j = 0; j < 4; ++j)
          acc[i][j] = __builtin_amdgcn_mfma_f32_16x16x32_bf16(af[i], bfr[j], acc[i][j], 0, 0, 0);
    }
  };

  stage(0, 0);
  __syncthreads();
  int cur = 0;
#pragma unroll
  for (int ks = 0; ks < 4; ++ks) {
    if (ks < 3) stage(cur ^ 1, (ks + 1) * 64);
    compute(cur);
    if (ks < 3) __syncthreads();
    cur ^= 1;
  }

  // epilogue
#pragma unroll
  for (int i = 0; i < 4; ++i) {
#pragma unroll
    for (int j = 0; j < 4; ++j) {
      int colg = n0 + wn + j * 16 + lr;
#pragma unroll
      for (int r = 0; r < 4; ++r) {
        int p = m0 + wm + i * 16 + g * 4 + r;
        float v = acc[i][j][r];
        if (nt < 2) {
          int yy = (p >> 7) & 127, xx = p & 127;
          int qi = (yy - min(max(yy, 2), 125) + 2) * 5 + (xx - min(max(xx, 2), 125) + 2);
          v += pos_emb[qi * 256 + colg];
          Qb[(size_t)p * 256 + colg] = f2bf(v);
        } else if (nt < 4) {
          Kb[(size_t)p * 256 + (colg - 256)] = f2bf(v);
        } else {
          Vb[(size_t)p * 256 + (colg - 512)] = f2bf(v);
        }
      }
    }
  }
}

// ---------------- attention: split-F, fused pe-dot, rolled loops (R5, unchanged) ----------------
__launch_bounds__(256, 4)
__global__ void attn_kernel(const short* __restrict__ Qb, const short* __restrict__ Kb,
                            const short* __restrict__ Vb, const float* __restrict__ pos_emb,
                            short* __restrict__ ACC) {
  __shared__ float pe[25 * 256];
  for (int i = threadIdx.x; i < 1600; i += 256) {
    float4 vv = reinterpret_cast<const float4*>(pos_emb)[i];
    int w = i * 4;
    int f = w & 255;
    int dst = (w & ~255) + (f ^ ((f >> 5) << 2));
    *reinterpret_cast<float4*>(pe + dst) = vv;
  }

  const int t = threadIdx.x;
  const int half = t & 1, h = (t >> 1) & 7, pl = t >> 4;
  const int id = blockIdx.x;
  const int b = id & 7;
  const int local = id >> 3;
  const int bx = local & 31, by = local >> 5;
  const int xx = bx * 4 + (pl & 3);
  const int yy = by * 4 + (pl >> 2);
  const int yc = min(max(yy, 2), 125), xc = min(max(xx, 2), 125);
  const int fo = h * 32 + half * 16;
  const int hx4 = h << 2;
  const size_t pbase = ((size_t)((b * 128 + yy) * 128 + xx)) * 256 + fo;
  const size_t cbase = ((size_t)((b * 128 + yc) * 128 + xc)) * 256 + fo;
  const float SCALE = 0.17677669529663689f;

  float q[16];
  {
    v8s q0 = *reinterpret_cast<const v8s*>(Qb + pbase);
    v8s q1 = *reinterpret_cast<const v8s*>(Qb + pbase + 8);
#pragma unroll
    for (int e = 0; e < 8; ++e) { q[e] = bf2f(q0[e]); q[8 + e] = bf2f(q1[e]); }
  }
  __syncthreads();

  float l = 0.f;
  float oa[16];
#pragma unroll
  for (int f = 0; f < 16; ++f) oa[f] = 0.f;

  const short* kb = Kb + cbase;
  const short* vb = Vb + cbase;
  const float* pb = pe + h * 32;
  const int j0 = (half * 16) ^ hx4;
  const int j1 = (half * 16 + 4) ^ hx4;
  const int j2 = (half * 16 + 8) ^ hx4;
  const int j3 = (half * 16 + 12) ^ hx4;

#pragma unroll 1
  for (int dy = -2; dy <= 2; ++dy) {
    const short* krow = kb + dy * (128 * 256);
    const short* vrow = vb + dy * (128 * 256);
    const float* prow = pb + ((dy + 2) * 5) * 256;
#pragma unroll 1
    for (int dx = -2; dx <= 2; ++dx) {
      const short* kp = krow + dx * 256;
      const short* vp = vrow + dx * 256;
      const float* pp = prow + (dx + 2) * 256;
      v8s k0 = *reinterpret_cast<const v8s*>(kp);
      v8s k1 = *reinterpret_cast<const v8s*>(kp + 8);
      v8s v0 = *reinterpret_cast<const v8s*>(vp);
      v8s v1 = *reinterpret_cast<const v8s*>(vp + 8);
      float4 p0 = *reinterpret_cast<const float4*>(pp + j0);
      float4 p1 = *reinterpret_cast<const float4*>(pp + j1);
      float4 p2 = *reinterpret_cast<const float4*>(pp + j2);
      float4 p3 = *reinterpret_cast<const float4*>(pp + j3);
      float d0 = 0.f, d1 = 0.f, d2 = 0.f, d3 = 0.f;
#pragma unroll
      for (int e = 0; e < 4; ++e) {
        d0 = fmaf(q[e], bf2f(k0[e]), d0);
        d1 = fmaf(q[4 + e], bf2f(k0[4 + e]), d1);
        d2 = fmaf(q[8 + e], bf2f(k1[e]), d2);
        d3 = fmaf(q[12 + e], bf2f(k1[4 + e]), d3);
      }
      d0 = fmaf(q[0], p0.x, d0); d0 = fmaf(q[1], p0.y, d0);
      d0 = fmaf(q[2], p0.z, d0); d0 = fmaf(q[3], p0.w, d0);
      d1 = fmaf(q[4], p1.x, d1); d1 = fmaf(q[5], p1.y, d1);
      d1 = fmaf(q[6], p1.z, d1); d1 = fmaf(q[7], p1.w, d1);
      d2 = fmaf(q[8], p2.x, d2); d2 = fmaf(q[9], p2.y, d2);
      d2 = fmaf(q[10], p2.z, d2); d2 = fmaf(q[11], p2.w, d2);
      d3 = fmaf(q[12], p3.x, d3); d3 = fmaf(q[13], p3.y, d3);
      d3 = fmaf(q[14], p3.z, d3); d3 = fmaf(q[15], p3.w, d3);
      float part = ((d0 + d1) + (d2 + d3)) * SCALE;
      float full = part + __shfl_xor(part, 1);
      float w = __expf(full);
      l += w;
#pragma unroll
      for (int e = 0; e < 8; ++e) oa[e] = fmaf(w, bf2f(v0[e]), oa[e]);
#pragma unroll
      for (int e = 0; e < 8; ++e) oa[8 + e] = fmaf(w, bf2f(v1[e]), oa[8 + e]);
    }
  }

  float inv = 1.f / l;
  v8s o0, o1;
#pragma unroll
  for (int e = 0; e < 8; ++e) { o0[e] = f2bf(oa[e] * inv); o1[e] = f2bf(oa[8 + e] * inv); }
  *reinterpret_cast<v8s*>(ACC + pbase) = o0;
  *reinterpret_cast<v8s*>(ACC + pbase + 8) = o1;
}

// ---------------- output projection GEMM: 128x128, BK=64, dbuf + global_load_lds ----------------
// grid 2048 (1024 m-tiles x 2 n-tiles), XCD-chunked.
__launch_bounds__(256, 2)
__global__ void out_gemm(const short* __restrict__ A, const short* __restrict__ WoT,
                         float* __restrict__ out) {
  __shared__ short As[2][128 * 64];
  __shared__ short Bs[2][128 * 64];
  const int t = threadIdx.x;
  const int bi = blockIdx.x;
  const int xcd = bi & 7;
  const int jj = bi >> 3;
  const int mt = (jj / 2) * 8 + xcd;   // bijective: 2048 % 8 == 0
  const int nt = jj % 2;
  const int m0 = mt * 128, n0 = nt * 128;
  const int wave = t >> 6, lane = t & 63;
  const int wm = (wave & 1) * 64, wn = (wave >> 1) * 64;
  const int lr = lane & 15, g = lane >> 4;

  const int ro = lane >> 3;
  const int colb = ((lane & 7) * 16) ^ (ro << 4);
  const char* aSrc = reinterpret_cast<const char*>(A + (size_t)(m0 + ro) * 256) + colb;
  const char* bSrc = reinterpret_cast<const char*>(WoT + (size_t)(n0 + ro) * 256) + colb;

  v4f acc[4][4];
#pragma unroll
  for (int i = 0; i < 4; ++i)
#pragma unroll
    for (int j = 0; j < 4; ++j) acc[i][j] = (v4f){0.f, 0.f, 0.f, 0.f};

  auto stage = [&](int buf, int kt) {
#pragma unroll
    for (int c = 0; c < 4; ++c) {
      int cc = wave * 4 + c;
      gld16(aSrc + (size_t)cc * 8 * 512 + kt * 2, (char*)As[buf] + cc * 1024);
      gld16(bSrc + (size_t)cc * 8 * 512 + kt * 2, (char*)Bs[buf] + cc * 1024);
    }
  };
  auto compute = [&](int buf) {
#pragma unroll
    for (int kk = 0; kk < 2; ++kk) {
      v8s af[4], bfr[4];
#pragma unroll
      for (int i = 0; i < 4; ++i) {
        int row = wm + i * 16 + lr;
        int byte = (row * 128 + kk * 64 + g * 16) ^ ((row & 7) << 4);
        af[i] = *reinterpret_cast<const v8s*>(reinterpret_cast<const char*>(As[buf]) + byte);
      }
#pragma unroll
      for (int j = 0; j < 4; ++j) {
        int rn = wn + j * 16 + lr;
        int byte = (rn * 128 + kk * 64 + g * 16) ^ ((rn & 7) << 4);
        bfr[j] = *reinterpret_cast<const v8s*>(reinterpret_cast<const char*>(Bs[buf]) + byte);
      }
#pragma unroll
      for (int i = 0; i < 4; ++i)
#pragma unroll
        for (int j = 0; j < 4; ++j)
          acc[i][j] = __builtin_amdgcn_mfma_f32_16x16x32_bf16(af[i], bfr[j], acc[i][j], 0, 0, 0);
    }
  };

  stage(0, 0);
  __syncthreads();
  int cur = 0;
#pragma unroll
  for (int ks = 0; ks < 4; ++ks) {
    if (ks < 3) stage(cur ^ 1, (ks + 1) * 64);
    compute(cur);
    if (ks < 3) __syncthreads();
    cur ^= 1;
  }

#pragma unroll
  for (int i = 0; i < 4; ++i) {
#pragma unroll
    for (int j = 0; j < 4; ++j) {
      int colg = n0 + wn + j * 16 + lr;
#pragma unroll
      for (int r = 0; r < 4; ++r) {
        int p = m0 + wm + i * 16 + g * 4 + r;
        out[(size_t)p * 256 + colg] = acc[i][j][r];
      }
    }
  }
}

extern "C" void kernel_launch(void* const* d_in, const int* in_sizes, int n_in,
                              void* d_out, int out_size, void* d_ws, size_t ws_size,
                              hipStream_t stream) {
  const float* x       = (const float*)d_in[0];
  const float* Wq      = (const float*)d_in[1];
  const float* Wk      = (const float*)d_in[2];
  const float* Wv      = (const float*)d_in[3];
  const float* Wout    = (const float*)d_in[4];
  const float* pos_emb = (const float*)d_in[5];
  float* out = (float*)d_out;

  char* ws = (char*)d_ws;
  short* WcT  = (short*)ws;                       // 768*256*2   = 393216 B
  short* WoT  = (short*)(ws + 393216);            // 256*256*2   = 131072 B
  short* Qb   = (short*)(ws + 524288);            // 131072*256*2 each
  short* Kb   = Qb + (size_t)131072 * 256;
  short* Vb   = Kb + (size_t)131072 * 256;
  short* ACCb = Vb + (size_t)131072 * 256;
  short* xb   = ACCb;   // alias: xb used only before attn writes ACCb

  prep_weights<<<768, 256, 0, stream>>>(Wq, Wk, Wv, Wout, WcT, WoT);
  x_cast<<<4096, 256, 0, stream>>>(x, xb);
  proj_gemm<<<6144, 256, 0, stream>>>(xb, WcT, pos_emb, Qb, Kb, Vb);
  attn_kernel<<<8192, 256, 0, stream>>>(Qb, Kb, Vb, pos_emb, ACCb);
  out_gemm<<<2048, 256, 0, stream>>>(ACCb, WoT, out);
}